// Round 8
// baseline (464.707 us; speedup 1.0000x reference)
//
#include <hip/hip_runtime.h>
#include <math.h>

#define BB 16
#define LL 512
#define DD 768
#define HH 12
#define DHH 64
#define SPDD 5
#define MM (BB*LL)   // 8192
#define LN_EPS 1e-5f
#define CLAMP_MINV 1e-6f

typedef __attribute__((ext_vector_type(8))) short bf8_t;
typedef __attribute__((ext_vector_type(4))) float f4_t;

__device__ __forceinline__ short f2bf(float x) {
    unsigned u = __builtin_bit_cast(unsigned, x);
    unsigned r = (u + 0x7FFFu + ((u >> 16) & 1u)) >> 16;
    return (short)r;
}
__device__ __forceinline__ float bf2f(short s) {
    unsigned u = ((unsigned)(unsigned short)s) << 16;
    return __builtin_bit_cast(float, u);
}

__device__ __forceinline__ void gld16(const short* g, short* l) {
    __builtin_amdgcn_global_load_lds(
        (const __attribute__((address_space(1))) unsigned int*)g,
        (__attribute__((address_space(3))) unsigned int*)l,
        16, 0, 0);
}

// ---------------- prep: input cast + weight transpose -----------------------
// blocks [0,3072): aqk = bf16(tgt+qpos), av = bf16(tgt)
// blocks [3072,3648): Wt[n][k] = bf16(W[k][n]) for 4 weights
__global__ __launch_bounds__(256) void prep_kernel(
    const float* __restrict__ tgt, const float* __restrict__ qpos,
    const float* __restrict__ W0, const float* __restrict__ W1,
    const float* __restrict__ W2, const float* __restrict__ W3,
    short* __restrict__ aqk, short* __restrict__ av,
    short* __restrict__ O0, short* __restrict__ O1,
    short* __restrict__ O2, short* __restrict__ O3)
{
    __shared__ float T[64][65];
    const int t = blockIdx.x;
    if (t < 3072) {
        // ---- input cast ----
        const size_t base = ((size_t)t * 256 + threadIdx.x) * 8;
        const float4 t0 = *(const float4*)(tgt + base);
        const float4 t1 = *(const float4*)(tgt + base + 4);
        const float4 p0 = *(const float4*)(qpos + base);
        const float4 p1 = *(const float4*)(qpos + base + 4);
        short v[8], q[8];
        v[0] = f2bf(t0.x); v[1] = f2bf(t0.y); v[2] = f2bf(t0.z); v[3] = f2bf(t0.w);
        v[4] = f2bf(t1.x); v[5] = f2bf(t1.y); v[6] = f2bf(t1.z); v[7] = f2bf(t1.w);
        q[0] = f2bf(t0.x + p0.x); q[1] = f2bf(t0.y + p0.y);
        q[2] = f2bf(t0.z + p0.z); q[3] = f2bf(t0.w + p0.w);
        q[4] = f2bf(t1.x + p1.x); q[5] = f2bf(t1.y + p1.y);
        q[6] = f2bf(t1.z + p1.z); q[7] = f2bf(t1.w + p1.w);
        *(bf8_t*)(av + base)  = *(bf8_t*)v;
        *(bf8_t*)(aqk + base) = *(bf8_t*)q;
    } else {
        // ---- weight transpose + cast ----
        const int wt = t - 3072;                // 0..575
        const int wi = wt / 144;
        const int rem = wt % 144;
        const float* W; short* O;
        switch (wi) {
            case 0: W = W0; O = O0; break;
            case 1: W = W1; O = O1; break;
            case 2: W = W2; O = O2; break;
            default: W = W3; O = O3; break;
        }
        const int n0 = (rem % 12) * 64, k0 = (rem / 12) * 64;
        const int tid = threadIdx.x;
        {
            const int kk = tid >> 4, nv = (tid & 15) * 4;
            #pragma unroll
            for (int i = 0; i < 4; ++i) {
                const int k = kk + i * 16;
                const float4 v = *(const float4*)(W + (size_t)(k0 + k) * DD + n0 + nv);
                T[k][nv + 0] = v.x; T[k][nv + 1] = v.y;
                T[k][nv + 2] = v.z; T[k][nv + 3] = v.w;
            }
        }
        __syncthreads();
        {
            const int n = tid >> 2, kc = (tid & 3) * 16;
            short tmp[16];
            #pragma unroll
            for (int i = 0; i < 16; ++i) tmp[i] = f2bf(T[kc + i][n]);
            short* dst = O + (size_t)(n0 + n) * DD + k0 + kc;
            *(bf8_t*)dst       = *(bf8_t*)tmp;
            *(bf8_t*)(dst + 8) = *(bf8_t*)(tmp + 8);
        }
    }
}

// ---------------- merged: Q/K/V MFMA GEMM + la-bias precompute --------------
// blocks [0,576): GEMM, two by-tiles each; all resident from t=0.
// blocks [576,2624): la = bf16(max(ploc·Wloc+bloc, 1e-6)) streaming behind.
__global__ __launch_bounds__(256) void qkv_la(
    const short* __restrict__ Aqk, const short* __restrict__ Av,
    const short* __restrict__ Wq, const float* __restrict__ bq, short* __restrict__ oq,
    const short* __restrict__ Wk, const float* __restrict__ bk, short* __restrict__ ok,
    const short* __restrict__ Wv, const float* __restrict__ bv, short* __restrict__ ov,
    const float* __restrict__ ploc, const float* __restrict__ Wloc,
    const float* __restrict__ bloc, short* __restrict__ la)
{
    __shared__ short As[128 * 64];
    __shared__ short Bs[128 * 64];
    const int id = blockIdx.x;

    if (id >= 576) {
        // ---- spatial la precompute (la block index 0..2047) ----
        const int lb  = id - 576;
        const int g   = lb * 256 + threadIdx.x;
        const int tch = g & 63;
        const int l   = (g >> 6) & 511;
        const int b   = g >> 15;
        const int t0  = tch * 8;
        float p[40];
        const float* src = ploc + (((size_t)b * LL + l) * LL + t0) * SPDD;
        #pragma unroll
        for (int i = 0; i < 10; ++i)
            *(float4*)(p + i * 4) = *(const float4*)(src + i * 4);
        #pragma unroll
        for (int h = 0; h < HH; ++h) {
            float wl[SPDD];
            #pragma unroll
            for (int s = 0; s < SPDD; ++s) wl[s] = Wloc[s * HH + h];
            const float bl = bloc[h];
            short o[8];
            #pragma unroll
            for (int i = 0; i < 8; ++i) {
                float v = bl;
                #pragma unroll
                for (int s = 0; s < SPDD; ++s) v += p[i * SPDD + s] * wl[s];
                o[i] = f2bf(fmaxf(v, CLAMP_MINV));   // relu+clip
            }
            *(bf8_t*)(la + (((size_t)(b * HH + h) * LL + l) * LL + t0)) = *(bf8_t*)o;
        }
        return;
    }

    // ---- GEMM path: id 0..575, two by-tiles each ----
    const int xcd = id & 7;
    const int jj  = id >> 3;                // 0..71
    const int gx  = jj / 4;                 // 0..17: seg/bx
    const int byp = jj % 4;                 // by-pair within XCD
    const int seg = gx / 6;
    const int bx  = gx % 6;
    const short* A  = (seg == 2) ? Av : Aqk;
    const short* Wt = (seg == 0) ? Wq : (seg == 1) ? Wk : Wv;
    const float* bias = (seg == 0) ? bq : (seg == 1) ? bk : bv;
    short* out = (seg == 0) ? oq : (seg == 1) ? ok : ov;

    const int n0 = bx * 128;
    const int tid = threadIdx.x;
    const int w = tid >> 6, lane = tid & 63;
    const int quad = lane >> 4, l16 = lane & 15;
    const int wm = w & 1, wn = w >> 1;
    const int sr = w * 8 + (lane >> 3);
    const int sp = lane & 7;

    float bvv[4];
    #pragma unroll
    for (int jb = 0; jb < 4; ++jb) bvv[jb] = bias[n0 + wn * 64 + jb * 16 + l16];

    for (int t = 0; t < 2; ++t) {
        const int by = xcd * 8 + byp * 2 + t;
        const int m0 = by * 128;

        f4_t acc[4][4];
        #pragma unroll
        for (int i = 0; i < 4; ++i)
            #pragma unroll
            for (int jb = 0; jb < 4; ++jb) acc[i][jb] = (f4_t){0.f, 0.f, 0.f, 0.f};

        for (int k0 = 0; k0 < DD; k0 += 64) {
            __syncthreads();
            #pragma unroll
            for (int ra = 0; ra < 4; ++ra) {
                const int r = sr + ra * 32;
                const int c = sp ^ (r & 7);
                const int ldso = ra * 2048 + w * 512 + lane * 8;
                gld16(A  + (size_t)(m0 + r) * DD + k0 + c * 8, As + ldso);
                gld16(Wt + (size_t)(n0 + r) * DD + k0 + c * 8, Bs + ldso);
            }
            __syncthreads();
            #pragma unroll
            for (int s = 0; s < 2; ++s) {
                bf8_t a[4], b[4];
                #pragma unroll
                for (int i = 0; i < 4; ++i) {
                    const int rA = wm * 64 + i * 16 + l16;
                    const int pA = (s * 4 + quad) ^ (rA & 7);
                    a[i] = *(const bf8_t*)(As + rA * 64 + pA * 8);
                    const int rB = wn * 64 + i * 16 + l16;
                    const int pB = (s * 4 + quad) ^ (rB & 7);
                    b[i] = *(const bf8_t*)(Bs + rB * 64 + pB * 8);
                }
                #pragma unroll
                for (int i = 0; i < 4; ++i)
                    #pragma unroll
                    for (int jb = 0; jb < 4; ++jb)
                        acc[i][jb] = __builtin_amdgcn_mfma_f32_16x16x32_bf16(a[i], b[jb], acc[i][jb], 0, 0, 0);
            }
        }

        #pragma unroll
        for (int i = 0; i < 4; ++i) {
            #pragma unroll
            for (int jb = 0; jb < 4; ++jb) {
                const int n = n0 + wn * 64 + jb * 16 + l16;
                #pragma unroll
                for (int r = 0; r < 4; ++r) {
                    const int m = m0 + wm * 64 + i * 16 + quad * 4 + r;
                    const float val = acc[i][jb][r] + bvv[jb];
                    const int b_ = m >> 9, l = m & 511;
                    const int h = n >> 6, d = n & 63;
                    if (seg < 2)
                        out[(((size_t)(b_ * HH + h)) * LL + l) * DHH + d] = f2bf(val);
                    else
                        out[(((size_t)(b_ * HH + h)) * DHH + d) * LL + l] = f2bf(val);
                }
            }
        }
    }
}

// ---------------- flash-style MFMA attention (8-wave, Q-tile 128) -----------
// grid 768 = 16b x 12h x 4qt, 512 thr: id%8 = XCD -> b pinned per XCD.
// 768 blocks @ 50KB LDS = 3 blocks/CU -> single residency round, no tail,
// 24 waves/CU (vs 12 for the 4-wave version). NO forced min-wave bound (the
// r3 regression was __launch_bounds__(512,6) squeezing to 40 VGPR -> spills).
// p = la * exp(s/8 - m). Block 767 zeroes the gemm_o panel counters after its
// loop (sole reader of the la tail bytes cnt may alias).
__global__ __launch_bounds__(512) void attn_mfma(
    const short* __restrict__ Q, const short* __restrict__ K,
    const short* __restrict__ Vt, const short* __restrict__ LA,
    short* __restrict__ out, int* __restrict__ cnt)
{
    __shared__ short Ks[64 * 64];
    __shared__ short Vs[64 * 64];
    __shared__ short bs16[128 * 68];
    __shared__ short Ps[8][16 * 64];

    const int id = blockIdx.x;
    const int xcd = id & 7, slot = id >> 3;       // slot: 0..95
    const int b = xcd + 8 * (slot / 48);
    const int s2 = slot % 48;
    const int h = s2 % 12, qt = s2 / 12;          // qt: 0..3

    const int tid = threadIdx.x;
    const int w = tid >> 6, lane = tid & 63;      // w: 0..7
    const int quad = lane >> 4, l16 = lane & 15;
    const int l8 = lane >> 3, c8 = lane & 7;
    const int q0 = qt * 128;
    const size_t bh = (size_t)b * HH + h;

    const int qr = q0 + w * 16 + l16;
    const bf8_t aq0 = *(const bf8_t*)(Q + (bh * LL + qr) * DHH + quad * 8);
    const bf8_t aq1 = *(const bf8_t*)(Q + (bh * LL + qr) * DHH + quad * 8 + 32);

    f4_t o[4];
    #pragma unroll
    for (int dj = 0; dj < 4; ++dj) o[dj] = (f4_t){0.f, 0.f, 0.f, 0.f};
    float m_row[4], l_row[4];
    #pragma unroll
    for (int r = 0; r < 4; ++r) { m_row[r] = -1e30f; l_row[r] = 0.f; }

    const short* Kg = K  + bh * LL * DHH;
    const short* Vg = Vt + bh * DHH * LL;
    const short* Bg = LA + (bh * LL + q0) * LL;

    // K/V stage: wave w rows w*8..w*8+7, 1 gld16 each (linear dest,
    // inverse-swizzled source; row key = l8 since w*8 ≡ 0 mod 8)
    const int srow = w * 8 + l8;
    const int ssc  = (c8 ^ l8) * 8;
    // la stage: thread covers row bl, 16 t-elems
    const int bl = tid >> 2, ts = (tid & 3) * 16;

    for (int t0 = 0; t0 < LL; t0 += 64) {
        __syncthreads();
        gld16(Kg + (size_t)(t0 + srow) * DHH + ssc, Ks + w * 512 + lane * 8);
        gld16(Vg + (size_t)srow * LL + t0 + ssc,    Vs + w * 512 + lane * 8);
        {
            const short* src = Bg + (size_t)bl * LL + t0 + ts;
            #pragma unroll
            for (int i = 0; i < 4; ++i)
                *(short4*)(bs16 + bl * 68 + ts + i * 4) = *(const short4*)(src + i * 4);
        }
        __syncthreads();

        // ---- S = Q K^T ----
        f4_t sv[4];
        #pragma unroll
        for (int j = 0; j < 4; ++j) {
            const int rB = j * 16 + l16;
            const int x = rB & 7;
            const bf8_t b0 = *(const bf8_t*)(Ks + rB * 64 + ((quad ^ x) * 8));
            const bf8_t b1 = *(const bf8_t*)(Ks + rB * 64 + (((quad + 4) ^ x) * 8));
            f4_t c = (f4_t){0.f, 0.f, 0.f, 0.f};
            c = __builtin_amdgcn_mfma_f32_16x16x32_bf16(aq0, b0, c, 0, 0, 0);
            c = __builtin_amdgcn_mfma_f32_16x16x32_bf16(aq1, b1, c, 0, 0, 0);
            sv[j] = c;
        }

        // ---- online softmax: p = la * exp(s/8 - m) ----
        #pragma unroll
        for (int r = 0; r < 4; ++r) {
            const int lrel = w * 16 + quad * 4 + r;
            float mx = fmaxf(fmaxf(sv[0][r], sv[1][r]), fmaxf(sv[2][r], sv[3][r]));
            mx = fmaxf(mx, __shfl_xor(mx, 1, 16));
            mx = fmaxf(mx, __shfl_xor(mx, 2, 16));
            mx = fmaxf(mx, __shfl_xor(mx, 4, 16));
            mx = fmaxf(mx, __shfl_xor(mx, 8, 16));
            const float mn = fmaxf(m_row[r], mx * 0.125f);
            const float al = __expf(m_row[r] - mn);
            m_row[r] = mn;
            float rs = 0.f;
            #pragma unroll
            for (int j = 0; j < 4; ++j) {
                const float lav = bf2f(bs16[lrel * 68 + j * 16 + l16]);
                const float p = lav * __expf(__builtin_fmaf(sv[j][r], 0.125f, -mn));
                sv[j][r] = p;
                rs += p;
            }
            rs += __shfl_xor(rs, 1, 16);
            rs += __shfl_xor(rs, 2, 16);
            rs += __shfl_xor(rs, 4, 16);
            rs += __shfl_xor(rs, 8, 16);
            l_row[r] = l_row[r] * al + rs;
            #pragma unroll
            for (int dj = 0; dj < 4; ++dj) o[dj][r] *= al;
        }
        // ---- P: C-layout -> swizzled LDS -> A-layout (per-wave buffer) ----
        short* Pw = Ps[w];
        #pragma unroll
        for (int r = 0; r < 4; ++r) {
            const int rp = quad * 4 + r, rp7 = rp & 7;
            #pragma unroll
            for (int j = 0; j < 4; ++j) {
                const int t = j * 16 + l16;
                Pw[rp * 64 + (((t >> 3) ^ rp7) * 8) + (t & 7)] = f2bf(sv[j][r]);
            }
        }
        const int m7 = l16 & 7;
        const bf8_t ap0 = *(const bf8_t*)(Pw + l16 * 64 + ((quad ^ m7) * 8));
        const bf8_t ap1 = *(const bf8_t*)(Pw + l16 * 64 + (((quad + 4) ^ m7) * 8));
        #pragma unroll
        for (int dj = 0; dj < 4; ++dj) {
            const int rB = dj * 16 + l16;
            const int x = rB & 7;
            const bf8_t b0 = *(const bf8_t*)(Vs + rB * 64 + ((quad ^ x) * 8));
            const bf8_t b1 = *(const bf8_t*)(Vs + rB * 64 + (((quad + 4) ^ x) * 8));
            o[dj] = __builtin_amdgcn_mfma_f32_16x16x32_bf16(ap0, b0, o[dj], 0, 0, 0);
            o[dj] = __builtin_amdgcn_mfma_f32_16x16x32_bf16(ap1, b1, o[dj], 0, 0, 0);
        }
    }

    // zero the gemm_o panel counters (sole reader of aliased la tail bytes)
    if (id == 767 && tid < 64) cnt[tid] = 0;

    #pragma unroll
    for (int r = 0; r < 4; ++r) {
        const int l = q0 + w * 16 + quad * 4 + r;
        const float inv = 1.f / l_row[r];
        short* op = out + ((size_t)b * LL + l) * DD + h * DHH;
        #pragma unroll
        for (int dj = 0; dj < 4; ++dj)
            op[dj * 16 + l16] = f2bf(o[dj][r] * inv);
    }
}

// ---------------- O-projection GEMM + distributed residual/LayerNorm --------
// All 384 blocks are co-resident (33KB LDS -> 4/CU, 384 < 1024), so a spin
// on the per-panel counter is deadlock-free. After the 6 blocks of an
// m-panel finish their tiles, they SPLIT the panel's 128 LN rows (~21 each,
// wave-per-row) — no r6-style 64-block tail.
__global__ __launch_bounds__(256) void gemm_o(
    const short* __restrict__ A, const short* __restrict__ Wt,
    const float* __restrict__ bias, float* __restrict__ out,
    const float* __restrict__ tgt, const float* __restrict__ lng,
    const float* __restrict__ lnb, float* __restrict__ fout,
    int* __restrict__ cnt)
{
    __shared__ short As[128 * 64];
    __shared__ short Bs[128 * 64];
    const int id = blockIdx.y * 6 + blockIdx.x;
    const int xcd = id & 7, j = id >> 3;          // j: 0..47
    const int by = xcd * 8 + j / 6;
    const int bx = j % 6;
    const int n0 = bx * 128, m0 = by * 128;
    const int tid = threadIdx.x;
    const int w = tid >> 6, lane = tid & 63;
    const int quad = lane >> 4, l16 = lane & 15;
    const int wm = w & 1, wn = w >> 1;
    const int sr = w * 8 + (lane >> 3);
    const int sp = lane & 7;

    f4_t acc[4][4];
    #pragma unroll
    for (int i = 0; i < 4; ++i)
        #pragma unroll
        for (int jj = 0; jj < 4; ++jj) acc[i][jj] = (f4_t){0.f, 0.f, 0.f, 0.f};

    for (int k0 = 0; k0 < DD; k0 += 64) {
        __syncthreads();
        #pragma unroll
        for (int ra = 0; ra < 4; ++ra) {
            const int r = sr + ra * 32;
            const int c = sp ^ (r & 7);
            const int ldso = ra * 2048 + w * 512 + lane * 8;
            gld16(A  + (size_t)(m0 + r) * DD + k0 + c * 8, As + ldso);
            gld16(Wt + (size_t)(n0 + r) * DD + k0 + c * 8, Bs + ldso);
        }
        __syncthreads();
        #pragma unroll
        for (int s = 0; s < 2; ++s) {
            bf8_t a[4], b[4];
            #pragma unroll
            for (int i = 0; i < 4; ++i) {
                const int rA = wm * 64 + i * 16 + l16;
                const int pA = (s * 4 + quad) ^ (rA & 7);
                a[i] = *(const bf8_t*)(As + rA * 64 + pA * 8);
                const int rB = wn * 64 + i * 16 + l16;
                const int pB = (s * 4 + quad) ^ (rB & 7);
                b[i] = *(const bf8_t*)(Bs + rB * 64 + pB * 8);
            }
            #pragma unroll
            for (int i = 0; i < 4; ++i)
                #pragma unroll
                for (int jj = 0; jj < 4; ++jj)
                    acc[i][jj] = __builtin_amdgcn_mfma_f32_16x16x32_bf16(a[i], b[jj], acc[i][jj], 0, 0, 0);
        }
    }

    float bvv[4];
    #pragma unroll
    for (int jj = 0; jj < 4; ++jj) bvv[jj] = bias[n0 + wn * 64 + jj * 16 + l16];
    #pragma unroll
    for (int i = 0; i < 4; ++i)
        #pragma unroll
        for (int jj = 0; jj < 4; ++jj) {
            const int n = n0 + wn * 64 + jj * 16 + l16;
            #pragma unroll
            for (int r = 0; r < 4; ++r) {
                const int m = m0 + wm * 64 + i * 16 + quad * 4 + r;
                out[(size_t)m * DD + n] = acc[i][jj][r] + bvv[jj];
            }
        }

    // ---- panel handshake: release, bump, spin till all 6 done -------------
    __threadfence();
    if (tid == 0) {
        atomicAdd(&cnt[by], 1);
        while (atomicAdd(&cnt[by], 0) < 6) __builtin_amdgcn_s_sleep(8);
    }
    __syncthreads();
    __threadfence();   // acquire: other tiles' writes now visible

    // ---- LN share: rows split 22,22,21,21,21,21 across the 6 blocks -------
    const int rs0   = bx * 21 + (bx < 2 ? bx : 2);
    const int nrows = 21 + (bx < 2 ? 1 : 0);
    float gv[12], bb[12];
    #pragma unroll
    for (int k = 0; k < 3; ++k) {
        const float4 gg = *(const float4*)(lng + lane * 4 + k * 256);
        const float4 b4 = *(const float4*)(lnb + lane * 4 + k * 256);
        gv[k*4+0] = gg.x; gv[k*4+1] = gg.y; gv[k*4+2] = gg.z; gv[k*4+3] = gg.w;
        bb[k*4+0] = b4.x; bb[k*4+1] = b4.y; bb[k*4+2] = b4.z; bb[k*4+3] = b4.w;
    }
    for (int rr = w; rr < nrows; rr += 4) {
        const int row = m0 + rs0 + rr;
        const float* xp = out + (size_t)row * DD;
        const float* tp = tgt + (size_t)row * DD;
        float v[12];
        float s = 0.f;
        #pragma unroll
        for (int k = 0; k < 3; ++k) {
            const float4 x = *(const float4*)(xp + lane * 4 + k * 256);
            const float4 t = *(const float4*)(tp + lane * 4 + k * 256);
            v[k*4+0] = x.x + t.x; v[k*4+1] = x.y + t.y;
            v[k*4+2] = x.z + t.z; v[k*4+3] = x.w + t.w;
            s += v[k*4+0] + v[k*4+1] + v[k*4+2] + v[k*4+3];
        }
        #pragma unroll
        for (int off = 32; off; off >>= 1) s += __shfl_xor(s, off, 64);
        const float mu = s * (1.f / 768.f);
        float vs = 0.f;
        #pragma unroll
        for (int e = 0; e < 12; ++e) { const float d = v[e] - mu; vs += d * d; }
        #pragma unroll
        for (int off = 32; off; off >>= 1) vs += __shfl_xor(vs, off, 64);
        const float rstd = rsqrtf(vs * (1.f / 768.f) + LN_EPS);
        float* op = fout + (size_t)row * DD;
        #pragma unroll
        for (int k = 0; k < 3; ++k) {
            float4 o;
            o.x = gv[k*4+0] * (v[k*4+0] - mu) * rstd + bb[k*4+0];
            o.y = gv[k*4+1] * (v[k*4+1] - mu) * rstd + bb[k*4+1];
            o.z = gv[k*4+2] * (v[k*4+2] - mu) * rstd + bb[k*4+2];
            o.w = gv[k*4+3] * (v[k*4+3] - mu) * rstd + bb[k*4+3];
            *(float4*)(op + lane * 4 + k * 256) = o;
        }
    }
}

// ---------------- launch -----------------------------------------------------
extern "C" void kernel_launch(void* const* d_in, const int* in_sizes, int n_in,
                              void* d_out, int out_size, void* d_ws, size_t ws_size,
                              hipStream_t stream) {
    const float* tgt   = (const float*)d_in[0];
    const float* qpos  = (const float*)d_in[1];
    const float* ploc  = (const float*)d_in[2];
    const float* Wq    = (const float*)d_in[3];
    const float* bq    = (const float*)d_in[4];
    const float* Wk    = (const float*)d_in[5];
    const float* bk    = (const float*)d_in[6];
    const float* Wv    = (const float*)d_in[7];
    const float* bv    = (const float*)d_in[8];
    const float* Wo    = (const float*)d_in[9];
    const float* bo    = (const float*)d_in[10];
    const float* Wloc  = (const float*)d_in[11];
    const float* bloc  = (const float*)d_in[12];
    const float* ln_g  = (const float*)d_in[13];
    const float* ln_b  = (const float*)d_in[14];

    const size_t NQ = (size_t)MM * DD;           // 6291456
    const size_t NW = (size_t)DD * DD;           // 589824

    short* qb   = (short*)d_ws;
    short* kb   = qb  + NQ;
    short* vtb  = kb  + NQ;
    short* aob  = vtb + NQ;
    short* aqk  = aob + NQ;
    short* av   = aqk + NQ;
    float* pbuf = (float*)aqk;                   // alias (aqk,av dead by then)
    short* wqt  = av + NQ;
    short* wkt  = wqt + NW;
    short* wvt  = wkt + NW;
    short* wot  = wvt + NW;
    short* lab  = wot + NW;
    // panel counters: last 256 B of the workspace (alias handled by attn 767)
    int*   cnt  = (int*)((char*)d_ws + ws_size - 256);

    prep_kernel<<<3648, 256, 0, stream>>>(tgt, qpos, Wq, Wk, Wv, Wo,
                                          aqk, av, wqt, wkt, wvt, wot);

    qkv_la<<<2624, 256, 0, stream>>>(aqk, av, wqt, bq, qb,
                                     wkt, bk, kb, wvt, bv, vtb,
                                     ploc, Wloc, bloc, lab);

    attn_mfma<<<768, 512, 0, stream>>>(qb, kb, vtb, lab, aob, cnt);

    gemm_o<<<dim3(6, 64), 256, 0, stream>>>(aob, wot, bo, pbuf,
                                            tgt, ln_g, ln_b, (float*)d_out, cnt);
}

// Round 9
// 349.518 us; speedup vs baseline: 1.3296x; 1.3296x over previous
//
#include <hip/hip_runtime.h>
#include <hip/hip_cooperative_groups.h>
#include <math.h>

namespace cg = cooperative_groups;

#define BB 16
#define LL 512
#define DD 768
#define HH 12
#define DHH 64
#define SPDD 5
#define MM (BB*LL)   // 8192
#define LN_EPS 1e-5f
#define CLAMP_MINV 1e-6f
#define SMEM_BYTES 33280

typedef __attribute__((ext_vector_type(8))) short bf8_t;
typedef __attribute__((ext_vector_type(4))) float f4_t;

__device__ __forceinline__ short f2bf(float x) {
    unsigned u = __builtin_bit_cast(unsigned, x);
    unsigned r = (u + 0x7FFFu + ((u >> 16) & 1u)) >> 16;
    return (short)r;
}
__device__ __forceinline__ float bf2f(short s) {
    unsigned u = ((unsigned)(unsigned short)s) << 16;
    return __builtin_bit_cast(float, u);
}

__device__ __forceinline__ void gld16(const short* g, short* l) {
    __builtin_amdgcn_global_load_lds(
        (const __attribute__((address_space(1))) unsigned int*)g,
        (__attribute__((address_space(3))) unsigned int*)l,
        16, 0, 0);
}

// ======================= phase bodies (shared by fused + fallback) ==========

// ---- prep: unit t in [0,3648) ----------------------------------------------
__device__ __forceinline__ void prep_body(int t, char* smemc,
    const float* __restrict__ tgt, const float* __restrict__ qpos,
    const float* __restrict__ W0, const float* __restrict__ W1,
    const float* __restrict__ W2, const float* __restrict__ W3,
    short* __restrict__ aqk, short* __restrict__ av,
    short* __restrict__ O0, short* __restrict__ O1,
    short* __restrict__ O2, short* __restrict__ O3)
{
    if (t < 3072) {
        // ---- input cast ----
        const size_t base = ((size_t)t * 256 + threadIdx.x) * 8;
        const float4 t0 = *(const float4*)(tgt + base);
        const float4 t1 = *(const float4*)(tgt + base + 4);
        const float4 p0 = *(const float4*)(qpos + base);
        const float4 p1 = *(const float4*)(qpos + base + 4);
        short v[8], q[8];
        v[0] = f2bf(t0.x); v[1] = f2bf(t0.y); v[2] = f2bf(t0.z); v[3] = f2bf(t0.w);
        v[4] = f2bf(t1.x); v[5] = f2bf(t1.y); v[6] = f2bf(t1.z); v[7] = f2bf(t1.w);
        q[0] = f2bf(t0.x + p0.x); q[1] = f2bf(t0.y + p0.y);
        q[2] = f2bf(t0.z + p0.z); q[3] = f2bf(t0.w + p0.w);
        q[4] = f2bf(t1.x + p1.x); q[5] = f2bf(t1.y + p1.y);
        q[6] = f2bf(t1.z + p1.z); q[7] = f2bf(t1.w + p1.w);
        *(bf8_t*)(av + base)  = *(bf8_t*)v;
        *(bf8_t*)(aqk + base) = *(bf8_t*)q;
    } else {
        // ---- weight transpose + cast ----
        float (*T)[65] = (float(*)[65])smemc;
        const int wt = t - 3072;                // 0..575
        const int wi = wt / 144;
        const int rem = wt % 144;
        const float* W; short* O;
        switch (wi) {
            case 0: W = W0; O = O0; break;
            case 1: W = W1; O = O1; break;
            case 2: W = W2; O = O2; break;
            default: W = W3; O = O3; break;
        }
        const int n0 = (rem % 12) * 64, k0 = (rem / 12) * 64;
        const int tid = threadIdx.x;
        {
            const int kk = tid >> 4, nv = (tid & 15) * 4;
            #pragma unroll
            for (int i = 0; i < 4; ++i) {
                const int k = kk + i * 16;
                const float4 v = *(const float4*)(W + (size_t)(k0 + k) * DD + n0 + nv);
                T[k][nv + 0] = v.x; T[k][nv + 1] = v.y;
                T[k][nv + 2] = v.z; T[k][nv + 3] = v.w;
            }
        }
        __syncthreads();
        {
            const int n = tid >> 2, kc = (tid & 3) * 16;
            short tmp[16];
            #pragma unroll
            for (int i = 0; i < 16; ++i) tmp[i] = f2bf(T[kc + i][n]);
            short* dst = O + (size_t)(n0 + n) * DD + k0 + kc;
            *(bf8_t*)dst       = *(bf8_t*)tmp;
            *(bf8_t*)(dst + 8) = *(bf8_t*)(tmp + 8);
        }
    }
}

// ---- qkv+la: unit u in [0,3200). [0,576) GEMM (2 by-tiles), rest la --------
__device__ __forceinline__ void qkv_la_body(int id, char* smemc,
    const short* __restrict__ Aqk, const short* __restrict__ Av,
    const short* __restrict__ Wq, const float* __restrict__ bq, short* __restrict__ oq,
    const short* __restrict__ Wk, const float* __restrict__ bk, short* __restrict__ ok,
    const short* __restrict__ Wv, const float* __restrict__ bv, short* __restrict__ ov,
    const float* __restrict__ ploc, const float* __restrict__ Wloc,
    const float* __restrict__ bloc, short* __restrict__ la)
{
    short* As = (short*)smemc;
    short* Bs = As + 128 * 64;

    if (id >= 576) {
        // ---- spatial la precompute (la block index 0..2047) ----
        const int lb  = id - 576;
        const int g   = lb * 256 + threadIdx.x;
        const int tch = g & 63;
        const int l   = (g >> 6) & 511;
        const int b   = g >> 15;
        const int t0  = tch * 8;
        float p[40];
        const float* src = ploc + (((size_t)b * LL + l) * LL + t0) * SPDD;
        #pragma unroll
        for (int i = 0; i < 10; ++i)
            *(float4*)(p + i * 4) = *(const float4*)(src + i * 4);
        #pragma unroll
        for (int h = 0; h < HH; ++h) {
            float wl[SPDD];
            #pragma unroll
            for (int s = 0; s < SPDD; ++s) wl[s] = Wloc[s * HH + h];
            const float bl = bloc[h];
            short o[8];
            #pragma unroll
            for (int i = 0; i < 8; ++i) {
                float v = bl;
                #pragma unroll
                for (int s = 0; s < SPDD; ++s) v += p[i * SPDD + s] * wl[s];
                o[i] = f2bf(fmaxf(v, CLAMP_MINV));   // relu+clip
            }
            *(bf8_t*)(la + (((size_t)(b * HH + h) * LL + l) * LL + t0)) = *(bf8_t*)o;
        }
        return;
    }

    // ---- GEMM path: id 0..575, two by-tiles each ----
    const int xcd = id & 7;
    const int jj  = id >> 3;                // 0..71
    const int gx  = jj / 4;                 // 0..17: seg/bx
    const int byp = jj % 4;                 // by-pair within XCD
    const int seg = gx / 6;
    const int bx  = gx % 6;
    const short* A  = (seg == 2) ? Av : Aqk;
    const short* Wt = (seg == 0) ? Wq : (seg == 1) ? Wk : Wv;
    const float* bias = (seg == 0) ? bq : (seg == 1) ? bk : bv;
    short* out = (seg == 0) ? oq : (seg == 1) ? ok : ov;

    const int n0 = bx * 128;
    const int tid = threadIdx.x;
    const int w = tid >> 6, lane = tid & 63;
    const int quad = lane >> 4, l16 = lane & 15;
    const int wm = w & 1, wn = w >> 1;
    const int sr = w * 8 + (lane >> 3);
    const int sp = lane & 7;

    float bvv[4];
    #pragma unroll
    for (int jb = 0; jb < 4; ++jb) bvv[jb] = bias[n0 + wn * 64 + jb * 16 + l16];

    for (int t = 0; t < 2; ++t) {
        const int by = xcd * 8 + byp * 2 + t;
        const int m0 = by * 128;

        f4_t acc[4][4];
        #pragma unroll
        for (int i = 0; i < 4; ++i)
            #pragma unroll
            for (int jb = 0; jb < 4; ++jb) acc[i][jb] = (f4_t){0.f, 0.f, 0.f, 0.f};

        for (int k0 = 0; k0 < DD; k0 += 64) {
            __syncthreads();
            #pragma unroll
            for (int ra = 0; ra < 4; ++ra) {
                const int r = sr + ra * 32;
                const int c = sp ^ (r & 7);
                const int ldso = ra * 2048 + w * 512 + lane * 8;
                gld16(A  + (size_t)(m0 + r) * DD + k0 + c * 8, As + ldso);
                gld16(Wt + (size_t)(n0 + r) * DD + k0 + c * 8, Bs + ldso);
            }
            __syncthreads();
            #pragma unroll
            for (int s = 0; s < 2; ++s) {
                bf8_t a[4], b[4];
                #pragma unroll
                for (int i = 0; i < 4; ++i) {
                    const int rA = wm * 64 + i * 16 + l16;
                    const int pA = (s * 4 + quad) ^ (rA & 7);
                    a[i] = *(const bf8_t*)(As + rA * 64 + pA * 8);
                    const int rB = wn * 64 + i * 16 + l16;
                    const int pB = (s * 4 + quad) ^ (rB & 7);
                    b[i] = *(const bf8_t*)(Bs + rB * 64 + pB * 8);
                }
                #pragma unroll
                for (int i = 0; i < 4; ++i)
                    #pragma unroll
                    for (int jb = 0; jb < 4; ++jb)
                        acc[i][jb] = __builtin_amdgcn_mfma_f32_16x16x32_bf16(a[i], b[jb], acc[i][jb], 0, 0, 0);
            }
        }

        #pragma unroll
        for (int i = 0; i < 4; ++i) {
            #pragma unroll
            for (int jb = 0; jb < 4; ++jb) {
                const int n = n0 + wn * 64 + jb * 16 + l16;
                #pragma unroll
                for (int r = 0; r < 4; ++r) {
                    const int m = m0 + wm * 64 + i * 16 + quad * 4 + r;
                    const float val = acc[i][jb][r] + bvv[jb];
                    const int b_ = m >> 9, l = m & 511;
                    const int h = n >> 6, d = n & 63;
                    if (seg < 2)
                        out[(((size_t)(b_ * HH + h)) * LL + l) * DHH + d] = f2bf(val);
                    else
                        out[(((size_t)(b_ * HH + h)) * DHH + d) * LL + l] = f2bf(val);
                }
            }
        }
    }
}

// ---- attn: unit u in [0,1536): x = u%192 (h + 12b), qt = u/192 -------------
__device__ __forceinline__ void attn_body(int u, char* smemc,
    const short* __restrict__ Q, const short* __restrict__ K,
    const short* __restrict__ Vt, const short* __restrict__ LA,
    short* __restrict__ out)
{
    short* Ks   = (short*)smemc;            // 4096 shorts
    short* Vs   = Ks + 4096;                // 4096
    short* bs16 = Vs + 4096;                // 64*68 = 4352
    short* Ps   = bs16 + 4352;              // 4*1024

    const int x = u % 192, qt = u / 192;
    const int h = x % 12, b = x / 12;
    const int tid = threadIdx.x;
    const int w = tid >> 6, lane = tid & 63;
    const int quad = lane >> 4, l16 = lane & 15;
    const int q0 = qt * 64;
    const size_t bh = (size_t)b * HH + h;

    const int qr = q0 + w * 16 + l16;
    const bf8_t aq0 = *(const bf8_t*)(Q + (bh * LL + qr) * DHH + quad * 8);
    const bf8_t aq1 = *(const bf8_t*)(Q + (bh * LL + qr) * DHH + quad * 8 + 32);

    f4_t o[4];
    #pragma unroll
    for (int dj = 0; dj < 4; ++dj) o[dj] = (f4_t){0.f, 0.f, 0.f, 0.f};
    float m_row[4], l_row[4];
    #pragma unroll
    for (int r = 0; r < 4; ++r) { m_row[r] = -1e30f; l_row[r] = 0.f; }

    const short* Kg = K  + bh * LL * DHH;
    const short* Vg = Vt + bh * DHH * LL;
    const short* Bg = LA + (bh * LL + q0) * LL;

    const int srow = tid >> 2;
    const int cb   = (tid & 3) * 2;
    const int sw   = srow & 7;

    for (int t0 = 0; t0 < LL; t0 += 64) {
        __syncthreads();
        {
            const short* src = Kg + (size_t)(t0 + srow) * DHH + cb * 8;
            *(bf8_t*)(Ks + srow * 64 + ((cb ^ sw) * 8))       = *(const bf8_t*)(src);
            *(bf8_t*)(Ks + srow * 64 + (((cb + 1) ^ sw) * 8)) = *(const bf8_t*)(src + 8);
        }
        {
            const short* src = Vg + (size_t)srow * LL + t0 + cb * 8;
            *(bf8_t*)(Vs + srow * 64 + ((cb ^ sw) * 8))       = *(const bf8_t*)(src);
            *(bf8_t*)(Vs + srow * 64 + (((cb + 1) ^ sw) * 8)) = *(const bf8_t*)(src + 8);
        }
        {
            const int l = tid >> 2, ts = (tid & 3) * 16;
            const short* src = Bg + (size_t)l * LL + t0 + ts;
            #pragma unroll
            for (int i = 0; i < 4; ++i)
                *(short4*)(bs16 + l * 68 + ts + i * 4) = *(const short4*)(src + i * 4);
        }
        __syncthreads();

        // ---- S = Q K^T ----
        f4_t sv[4];
        #pragma unroll
        for (int j = 0; j < 4; ++j) {
            const int rB = j * 16 + l16;
            const int xx = rB & 7;
            const bf8_t b0 = *(const bf8_t*)(Ks + rB * 64 + ((quad ^ xx) * 8));
            const bf8_t b1 = *(const bf8_t*)(Ks + rB * 64 + (((quad + 4) ^ xx) * 8));
            f4_t c = (f4_t){0.f, 0.f, 0.f, 0.f};
            c = __builtin_amdgcn_mfma_f32_16x16x32_bf16(aq0, b0, c, 0, 0, 0);
            c = __builtin_amdgcn_mfma_f32_16x16x32_bf16(aq1, b1, c, 0, 0, 0);
            sv[j] = c;
        }

        // ---- online softmax: p = la * exp(s/8 - m) ----
        #pragma unroll
        for (int r = 0; r < 4; ++r) {
            const int lrel = w * 16 + quad * 4 + r;
            float mx = fmaxf(fmaxf(sv[0][r], sv[1][r]), fmaxf(sv[2][r], sv[3][r]));
            mx = fmaxf(mx, __shfl_xor(mx, 1, 16));
            mx = fmaxf(mx, __shfl_xor(mx, 2, 16));
            mx = fmaxf(mx, __shfl_xor(mx, 4, 16));
            mx = fmaxf(mx, __shfl_xor(mx, 8, 16));
            const float mn = fmaxf(m_row[r], mx * 0.125f);
            const float al = __expf(m_row[r] - mn);
            m_row[r] = mn;
            float rs = 0.f;
            #pragma unroll
            for (int j = 0; j < 4; ++j) {
                const float lav = bf2f(bs16[lrel * 68 + j * 16 + l16]);
                const float p = lav * __expf(__builtin_fmaf(sv[j][r], 0.125f, -mn));
                sv[j][r] = p;
                rs += p;
            }
            rs += __shfl_xor(rs, 1, 16);
            rs += __shfl_xor(rs, 2, 16);
            rs += __shfl_xor(rs, 4, 16);
            rs += __shfl_xor(rs, 8, 16);
            l_row[r] = l_row[r] * al + rs;
            #pragma unroll
            for (int dj = 0; dj < 4; ++dj) o[dj][r] *= al;
        }
        // ---- P: C-layout -> swizzled LDS -> A-layout ----
        short* Pw = Ps + w * 1024;
        #pragma unroll
        for (int r = 0; r < 4; ++r) {
            const int rp = quad * 4 + r, rp7 = rp & 7;
            #pragma unroll
            for (int j = 0; j < 4; ++j) {
                const int t = j * 16 + l16;
                Pw[rp * 64 + (((t >> 3) ^ rp7) * 8) + (t & 7)] = f2bf(sv[j][r]);
            }
        }
        const int m7 = l16 & 7;
        const bf8_t ap0 = *(const bf8_t*)(Pw + l16 * 64 + ((quad ^ m7) * 8));
        const bf8_t ap1 = *(const bf8_t*)(Pw + l16 * 64 + (((quad + 4) ^ m7) * 8));
        #pragma unroll
        for (int dj = 0; dj < 4; ++dj) {
            const int rB = dj * 16 + l16;
            const int xx = rB & 7;
            const bf8_t b0 = *(const bf8_t*)(Vs + rB * 64 + ((quad ^ xx) * 8));
            const bf8_t b1 = *(const bf8_t*)(Vs + rB * 64 + (((quad + 4) ^ xx) * 8));
            o[dj] = __builtin_amdgcn_mfma_f32_16x16x32_bf16(ap0, b0, o[dj], 0, 0, 0);
            o[dj] = __builtin_amdgcn_mfma_f32_16x16x32_bf16(ap1, b1, o[dj], 0, 0, 0);
        }
    }

    #pragma unroll
    for (int r = 0; r < 4; ++r) {
        const int l = q0 + w * 16 + quad * 4 + r;
        const float inv = 1.f / l_row[r];
        short* op = out + ((size_t)b * LL + l) * DD + h * DHH;
        #pragma unroll
        for (int dj = 0; dj < 4; ++dj)
            op[dj * 16 + l16] = f2bf(o[dj][r] * inv);
    }
}

// ---- gemm_o: unit u in [0,384) ---------------------------------------------
__device__ __forceinline__ void gemm_o_body(int id, char* smemc,
    const short* __restrict__ A, const short* __restrict__ Wt,
    const float* __restrict__ bias, float* __restrict__ out)
{
    short* As = (short*)smemc;
    short* Bs = As + 128 * 64;
    const int xcd = id & 7, j = id >> 3;          // j: 0..47
    const int by = xcd * 8 + j / 6;
    const int bx = j % 6;
    const int n0 = bx * 128, m0 = by * 128;
    const int tid = threadIdx.x;
    const int w = tid >> 6, lane = tid & 63;
    const int quad = lane >> 4, l16 = lane & 15;
    const int wm = w & 1, wn = w >> 1;
    const int sr = w * 8 + (lane >> 3);
    const int sp = lane & 7;

    f4_t acc[4][4];
    #pragma unroll
    for (int i = 0; i < 4; ++i)
        #pragma unroll
        for (int jj = 0; jj < 4; ++jj) acc[i][jj] = (f4_t){0.f, 0.f, 0.f, 0.f};

    for (int k0 = 0; k0 < DD; k0 += 64) {
        __syncthreads();
        #pragma unroll
        for (int ra = 0; ra < 4; ++ra) {
            const int r = sr + ra * 32;
            const int c = sp ^ (r & 7);
            const int ldso = ra * 2048 + w * 512 + lane * 8;
            gld16(A  + (size_t)(m0 + r) * DD + k0 + c * 8, As + ldso);
            gld16(Wt + (size_t)(n0 + r) * DD + k0 + c * 8, Bs + ldso);
        }
        __syncthreads();
        #pragma unroll
        for (int s = 0; s < 2; ++s) {
            bf8_t a[4], b[4];
            #pragma unroll
            for (int i = 0; i < 4; ++i) {
                const int rA = wm * 64 + i * 16 + l16;
                const int pA = (s * 4 + quad) ^ (rA & 7);
                a[i] = *(const bf8_t*)(As + rA * 64 + pA * 8);
                const int rB = wn * 64 + i * 16 + l16;
                const int pB = (s * 4 + quad) ^ (rB & 7);
                b[i] = *(const bf8_t*)(Bs + rB * 64 + pB * 8);
            }
            #pragma unroll
            for (int i = 0; i < 4; ++i)
                #pragma unroll
                for (int jj = 0; jj < 4; ++jj)
                    acc[i][jj] = __builtin_amdgcn_mfma_f32_16x16x32_bf16(a[i], b[jj], acc[i][jj], 0, 0, 0);
        }
    }

    float bvv[4];
    #pragma unroll
    for (int jj = 0; jj < 4; ++jj) bvv[jj] = bias[n0 + wn * 64 + jj * 16 + l16];
    #pragma unroll
    for (int i = 0; i < 4; ++i)
        #pragma unroll
        for (int jj = 0; jj < 4; ++jj) {
            const int n = n0 + wn * 64 + jj * 16 + l16;
            #pragma unroll
            for (int r = 0; r < 4; ++r) {
                const int m = m0 + wm * 64 + i * 16 + quad * 4 + r;
                out[(size_t)m * DD + n] = acc[i][jj][r] + bvv[jj];
            }
        }
}

// ---- ln: unit = row in [0,8192) --------------------------------------------
__device__ __forceinline__ float block_sum(float v, float* red, int tid) {
    #pragma unroll
    for (int off = 32; off; off >>= 1) v += __shfl_down(v, off, 64);
    __syncthreads();
    if ((tid & 63) == 0) red[tid >> 6] = v;
    __syncthreads();
    return red[0] + red[1] + red[2] + red[3];
}

__device__ __forceinline__ void ln_body(int row, char* smemc,
    const float* __restrict__ x, const float* __restrict__ tgt,
    const float* __restrict__ g, const float* __restrict__ bta,
    float* __restrict__ out)
{
    float* red = (float*)smemc;
    const int tid = threadIdx.x;
    const float* xp = x + (size_t)row * DD;
    const float* tp = tgt + (size_t)row * DD;

    float vals[3];
    float s = 0.f;
    #pragma unroll
    for (int i = 0; i < 3; ++i) {
        const float v = xp[tid + i * 256] + tp[tid + i * 256];
        vals[i] = v;
        s += v;
    }
    s = block_sum(s, red, tid);
    const float mu = s * (1.f / 768.f);

    float vs = 0.f;
    #pragma unroll
    for (int i = 0; i < 3; ++i) {
        const float dv = vals[i] - mu;
        vs += dv * dv;
    }
    vs = block_sum(vs, red, tid);
    const float rstd = rsqrtf(vs * (1.f / 768.f) + LN_EPS);

    #pragma unroll
    for (int i = 0; i < 3; ++i) {
        const int cidx = tid + i * 256;
        out[(size_t)row * DD + cidx] = g[cidx] * (vals[i] - mu) * rstd + bta[cidx];
    }
}

// ======================= fused cooperative kernel ===========================
// One launch, 4 grid.sync()s instead of 4 inter-kernel gaps (~25 us each).
// Grid is sized by the occupancy API (host side) so all blocks are resident;
// every phase is grid-strided (stride % 8 == 0 preserves the XCD pinning).
__global__ __launch_bounds__(256) void fused_all(
    const float* __restrict__ tgt, const float* __restrict__ qpos,
    const float* __restrict__ ploc,
    const float* __restrict__ Wq, const float* __restrict__ bq,
    const float* __restrict__ Wk, const float* __restrict__ bk,
    const float* __restrict__ Wv, const float* __restrict__ bv,
    const float* __restrict__ Wo, const float* __restrict__ bo,
    const float* __restrict__ Wloc, const float* __restrict__ bloc,
    const float* __restrict__ ln_g, const float* __restrict__ ln_b,
    short* aqk, short* av,
    short* wqt, short* wkt, short* wvt, short* wot, short* lab,
    short* qb, short* kb, short* vtb, short* aob,
    float* pbuf, float* outp)
{
    __shared__ __align__(16) char smem[SMEM_BYTES];
    cg::grid_group grid = cg::this_grid();
    const int G = gridDim.x;
    const int bid = blockIdx.x;

    // phase 1: prep (cast + weight transpose)
    for (int u = bid; u < 3648; u += G) {
        __syncthreads();
        prep_body(u, smem, tgt, qpos, Wq, Wk, Wv, Wo,
                  aqk, av, wqt, wkt, wvt, wot);
    }
    __threadfence();
    grid.sync();

    // phase 2: Q/K/V GEMM (units 0..575, first pass) + la stream behind
    for (int u = bid; u < 3200; u += G) {
        __syncthreads();
        qkv_la_body(u, smem, aqk, av, wqt, bq, qb, wkt, bk, kb,
                    wvt, bv, vtb, ploc, Wloc, bloc, lab);
    }
    __threadfence();
    grid.sync();

    // phase 3: attention
    for (int u = bid; u < 1536; u += G) {
        __syncthreads();
        attn_body(u, smem, qb, kb, vtb, lab, aob);
    }
    __threadfence();
    grid.sync();

    // phase 4: O-projection
    for (int u = bid; u < 384; u += G) {
        __syncthreads();
        gemm_o_body(u, smem, aob, wot, bo, pbuf);
    }
    __threadfence();
    grid.sync();

    // phase 5: residual + LayerNorm
    for (int u = bid; u < MM; u += G) {
        __syncthreads();
        ln_body(u, smem, pbuf, tgt, ln_g, ln_b, outp);
    }
}

// ======================= fallback standalone kernels ========================

__global__ __launch_bounds__(256) void prep_kernel(
    const float* __restrict__ tgt, const float* __restrict__ qpos,
    const float* __restrict__ W0, const float* __restrict__ W1,
    const float* __restrict__ W2, const float* __restrict__ W3,
    short* __restrict__ aqk, short* __restrict__ av,
    short* __restrict__ O0, short* __restrict__ O1,
    short* __restrict__ O2, short* __restrict__ O3)
{
    __shared__ __align__(16) char smem[16704];
    prep_body(blockIdx.x, smem, tgt, qpos, W0, W1, W2, W3,
              aqk, av, O0, O1, O2, O3);
}

__global__ __launch_bounds__(256) void qkv_la(
    const short* __restrict__ Aqk, const short* __restrict__ Av,
    const short* __restrict__ Wq, const float* __restrict__ bq, short* __restrict__ oq,
    const short* __restrict__ Wk, const float* __restrict__ bk, short* __restrict__ ok,
    const short* __restrict__ Wv, const float* __restrict__ bv, short* __restrict__ ov,
    const float* __restrict__ ploc, const float* __restrict__ Wloc,
    const float* __restrict__ bloc, short* __restrict__ la)
{
    __shared__ __align__(16) char smem[32768];
    qkv_la_body(blockIdx.x, smem, Aqk, Av, Wq, bq, oq, Wk, bk, ok,
                Wv, bv, ov, ploc, Wloc, bloc, la);
}

__global__ __launch_bounds__(256) void attn_mfma(
    const short* __restrict__ Q, const short* __restrict__ K,
    const short* __restrict__ Vt, const short* __restrict__ LA,
    short* __restrict__ out)
{
    __shared__ __align__(16) char smem[SMEM_BYTES];
    attn_body(blockIdx.x, smem, Q, K, Vt, LA, out);
}

__global__ __launch_bounds__(256) void gemm_o(
    const short* __restrict__ A, const short* __restrict__ Wt,
    const float* __restrict__ bias, float* __restrict__ out)
{
    __shared__ __align__(16) char smem[32768];
    gemm_o_body(blockIdx.x, smem, A, Wt, bias, out);
}

__global__ __launch_bounds__(256) void ln_kernel(
    const float* __restrict__ x, const float* __restrict__ tgt,
    const float* __restrict__ g, const float* __restrict__ bta,
    float* __restrict__ out)
{
    __shared__ __align__(16) char smem[64];
    ln_body(blockIdx.x, smem, x, tgt, g, bta, out);
}

// ---------------- launch -----------------------------------------------------
extern "C" void kernel_launch(void* const* d_in, const int* in_sizes, int n_in,
                              void* d_out, int out_size, void* d_ws, size_t ws_size,
                              hipStream_t stream) {
    const float* tgt   = (const float*)d_in[0];
    const float* qpos  = (const float*)d_in[1];
    const float* ploc  = (const float*)d_in[2];
    const float* Wq    = (const float*)d_in[3];
    const float* bq    = (const float*)d_in[4];
    const float* Wk    = (const float*)d_in[5];
    const float* bk    = (const float*)d_in[6];
    const float* Wv    = (const float*)d_in[7];
    const float* bv    = (const float*)d_in[8];
    const float* Wo    = (const float*)d_in[9];
    const float* bo    = (const float*)d_in[10];
    const float* Wloc  = (const float*)d_in[11];
    const float* bloc  = (const float*)d_in[12];
    const float* ln_g  = (const float*)d_in[13];
    const float* ln_b  = (const float*)d_in[14];

    const size_t NQ = (size_t)MM * DD;           // 6291456
    const size_t NW = (size_t)DD * DD;           // 589824

    short* qb   = (short*)d_ws;
    short* kb   = qb  + NQ;
    short* vtb  = kb  + NQ;
    short* aob  = vtb + NQ;
    short* aqk  = aob + NQ;
    short* av   = aqk + NQ;
    float* pbuf = (float*)aqk;                   // alias (aqk,av dead by then)
    short* wqt  = av + NQ;
    short* wkt  = wqt + NW;
    short* wvt  = wkt + NW;
    short* wot  = wvt + NW;
    short* lab  = wot + NW;
    float* outp = (float*)d_out;

    // ---- cooperative grid sizing (cached) ----
    static int coop_grid = -2;                   // -2 = not yet probed
    if (coop_grid == -2) {
        int nb = 0;
        if (hipOccupancyMaxActiveBlocksPerMultiprocessor(&nb, fused_all, 256, 0)
                != hipSuccess || nb < 1) {
            coop_grid = -1;                      // cooperative path unusable
        } else {
            int ncu = 0;
            if (hipDeviceGetAttribute(&ncu, hipDeviceAttributeMultiprocessorCount, 0)
                    != hipSuccess || ncu <= 0) ncu = 256;
            long g = (long)nb * ncu;
            if (g > 3648) g = 3648;
            g -= (g % 8);                        // preserve XCD pinning
            if (g < 8) g = 8;
            coop_grid = (int)g;
        }
    }

    bool launched = false;
    if (coop_grid > 0) {
        void* kargs[] = {
            (void*)&tgt, (void*)&qpos, (void*)&ploc,
            (void*)&Wq, (void*)&bq, (void*)&Wk, (void*)&bk,
            (void*)&Wv, (void*)&bv, (void*)&Wo, (void*)&bo,
            (void*)&Wloc, (void*)&bloc, (void*)&ln_g, (void*)&ln_b,
            (void*)&aqk, (void*)&av,
            (void*)&wqt, (void*)&wkt, (void*)&wvt, (void*)&wot, (void*)&lab,
            (void*)&qb, (void*)&kb, (void*)&vtb, (void*)&aob,
            (void*)&pbuf, (void*)&outp
        };
        hipError_t err = hipLaunchCooperativeKernel(
            reinterpret_cast<const void*>(fused_all),
            dim3(coop_grid), dim3(256), kargs, 0, stream);
        if (err == hipSuccess) {
            launched = true;
        } else {
            coop_grid = -1;                      // never retry
            (void)hipGetLastError();             // clear error state
        }
    }

    if (!launched) {
        // ---- fallback: the proven 5-kernel r7 pipeline ----
        prep_kernel<<<3648, 256, 0, stream>>>(tgt, qpos, Wq, Wk, Wv, Wo,
                                              aqk, av, wqt, wkt, wvt, wot);
        qkv_la<<<2624, 256, 0, stream>>>(aqk, av, wqt, bq, qb,
                                         wkt, bk, kb, wvt, bv, vtb,
                                         ploc, Wloc, bloc, lab);
        attn_mfma<<<1536, 256, 0, stream>>>(qb, kb, vtb, lab, aob);
        gemm_o<<<384, 256, 0, stream>>>(aob, wot, bo, pbuf);
        ln_kernel<<<MM, 256, 0, stream>>>(pbuf, tgt, ln_g, ln_b, outp);
    }
}

// Round 10
// 348.490 us; speedup vs baseline: 1.3335x; 1.0029x over previous
//
#include <hip/hip_runtime.h>
#include <math.h>

#define BB 16
#define LL 512
#define DD 768
#define HH 12
#define DHH 64
#define SPDD 5
#define MM (BB*LL)   // 8192
#define LN_EPS 1e-5f
#define CLAMP_MINV 1e-6f

typedef __attribute__((ext_vector_type(8))) short bf8_t;
typedef __attribute__((ext_vector_type(4))) float f4_t;

__device__ __forceinline__ short f2bf(float x) {
    unsigned u = __builtin_bit_cast(unsigned, x);
    unsigned r = (u + 0x7FFFu + ((u >> 16) & 1u)) >> 16;
    return (short)r;
}
__device__ __forceinline__ float bf2f(short s) {
    unsigned u = ((unsigned)(unsigned short)s) << 16;
    return __builtin_bit_cast(float, u);
}

__device__ __forceinline__ void gld16(const short* g, short* l) {
    __builtin_amdgcn_global_load_lds(
        (const __attribute__((address_space(1))) unsigned int*)g,
        (__attribute__((address_space(3))) unsigned int*)l,
        16, 0, 0);
}

// ---------------- block reduce (256 threads, wave64) ------------------------
__device__ __forceinline__ float block_sum(float v, float* red, int tid) {
    #pragma unroll
    for (int off = 32; off; off >>= 1) v += __shfl_down(v, off, 64);
    __syncthreads();
    if ((tid & 63) == 0) red[tid >> 6] = v;
    __syncthreads();
    return red[0] + red[1] + red[2] + red[3];
}

// ---------------- prep: input cast + weight transpose -----------------------
// blocks [0,3072): aqk = bf16(tgt+qpos), av = bf16(tgt)
// blocks [3072,3648): Wt[n][k] = bf16(W[k][n]) for 4 weights
__global__ __launch_bounds__(256) void prep_kernel(
    const float* __restrict__ tgt, const float* __restrict__ qpos,
    const float* __restrict__ W0, const float* __restrict__ W1,
    const float* __restrict__ W2, const float* __restrict__ W3,
    short* __restrict__ aqk, short* __restrict__ av,
    short* __restrict__ O0, short* __restrict__ O1,
    short* __restrict__ O2, short* __restrict__ O3)
{
    __shared__ float T[64][65];
    const int t = blockIdx.x;
    if (t < 3072) {
        // ---- input cast ----
        const size_t base = ((size_t)t * 256 + threadIdx.x) * 8;
        const float4 t0 = *(const float4*)(tgt + base);
        const float4 t1 = *(const float4*)(tgt + base + 4);
        const float4 p0 = *(const float4*)(qpos + base);
        const float4 p1 = *(const float4*)(qpos + base + 4);
        short v[8], q[8];
        v[0] = f2bf(t0.x); v[1] = f2bf(t0.y); v[2] = f2bf(t0.z); v[3] = f2bf(t0.w);
        v[4] = f2bf(t1.x); v[5] = f2bf(t1.y); v[6] = f2bf(t1.z); v[7] = f2bf(t1.w);
        q[0] = f2bf(t0.x + p0.x); q[1] = f2bf(t0.y + p0.y);
        q[2] = f2bf(t0.z + p0.z); q[3] = f2bf(t0.w + p0.w);
        q[4] = f2bf(t1.x + p1.x); q[5] = f2bf(t1.y + p1.y);
        q[6] = f2bf(t1.z + p1.z); q[7] = f2bf(t1.w + p1.w);
        *(bf8_t*)(av + base)  = *(bf8_t*)v;
        *(bf8_t*)(aqk + base) = *(bf8_t*)q;
    } else {
        // ---- weight transpose + cast ----
        const int wt = t - 3072;                // 0..575
        const int wi = wt / 144;
        const int rem = wt % 144;
        const float* W; short* O;
        switch (wi) {
            case 0: W = W0; O = O0; break;
            case 1: W = W1; O = O1; break;
            case 2: W = W2; O = O2; break;
            default: W = W3; O = O3; break;
        }
        const int n0 = (rem % 12) * 64, k0 = (rem / 12) * 64;
        const int tid = threadIdx.x;
        {
            const int kk = tid >> 4, nv = (tid & 15) * 4;
            #pragma unroll
            for (int i = 0; i < 4; ++i) {
                const int k = kk + i * 16;
                const float4 v = *(const float4*)(W + (size_t)(k0 + k) * DD + n0 + nv);
                T[k][nv + 0] = v.x; T[k][nv + 1] = v.y;
                T[k][nv + 2] = v.z; T[k][nv + 3] = v.w;
            }
        }
        __syncthreads();
        {
            const int n = tid >> 2, kc = (tid & 3) * 16;
            short tmp[16];
            #pragma unroll
            for (int i = 0; i < 16; ++i) tmp[i] = f2bf(T[kc + i][n]);
            short* dst = O + (size_t)(n0 + n) * DD + k0 + kc;
            *(bf8_t*)dst       = *(bf8_t*)tmp;
            *(bf8_t*)(dst + 8) = *(bf8_t*)(tmp + 8);
        }
    }
}

// ---------------- merged: Q/K/V MFMA GEMM + la-bias precompute --------------
// blocks [0,576): GEMM, two by-tiles each; all resident from t=0.
// blocks [576,2624): la = bf16(max(ploc·Wloc+bloc, 1e-6)) streaming behind.
__global__ __launch_bounds__(256) void qkv_la(
    const short* __restrict__ Aqk, const short* __restrict__ Av,
    const short* __restrict__ Wq, const float* __restrict__ bq, short* __restrict__ oq,
    const short* __restrict__ Wk, const float* __restrict__ bk, short* __restrict__ ok,
    const short* __restrict__ Wv, const float* __restrict__ bv, short* __restrict__ ov,
    const float* __restrict__ ploc, const float* __restrict__ Wloc,
    const float* __restrict__ bloc, short* __restrict__ la)
{
    __shared__ short As[128 * 64];
    __shared__ short Bs[128 * 64];
    const int id = blockIdx.x;

    if (id >= 576) {
        // ---- spatial la precompute (la block index 0..2047) ----
        const int lb  = id - 576;
        const int g   = lb * 256 + threadIdx.x;
        const int tch = g & 63;
        const int l   = (g >> 6) & 511;
        const int b   = g >> 15;
        const int t0  = tch * 8;
        float p[40];
        const float* src = ploc + (((size_t)b * LL + l) * LL + t0) * SPDD;
        #pragma unroll
        for (int i = 0; i < 10; ++i)
            *(float4*)(p + i * 4) = *(const float4*)(src + i * 4);
        #pragma unroll
        for (int h = 0; h < HH; ++h) {
            float wl[SPDD];
            #pragma unroll
            for (int s = 0; s < SPDD; ++s) wl[s] = Wloc[s * HH + h];
            const float bl = bloc[h];
            short o[8];
            #pragma unroll
            for (int i = 0; i < 8; ++i) {
                float v = bl;
                #pragma unroll
                for (int s = 0; s < SPDD; ++s) v += p[i * SPDD + s] * wl[s];
                o[i] = f2bf(fmaxf(v, CLAMP_MINV));   // relu+clip
            }
            *(bf8_t*)(la + (((size_t)(b * HH + h) * LL + l) * LL + t0)) = *(bf8_t*)o;
        }
        return;
    }

    // ---- GEMM path: id 0..575, two by-tiles each ----
    const int xcd = id & 7;
    const int jj  = id >> 3;                // 0..71
    const int gx  = jj / 4;                 // 0..17: seg/bx
    const int byp = jj % 4;                 // by-pair within XCD
    const int seg = gx / 6;
    const int bx  = gx % 6;
    const short* A  = (seg == 2) ? Av : Aqk;
    const short* Wt = (seg == 0) ? Wq : (seg == 1) ? Wk : Wv;
    const float* bias = (seg == 0) ? bq : (seg == 1) ? bk : bv;
    short* out = (seg == 0) ? oq : (seg == 1) ? ok : ov;

    const int n0 = bx * 128;
    const int tid = threadIdx.x;
    const int w = tid >> 6, lane = tid & 63;
    const int quad = lane >> 4, l16 = lane & 15;
    const int wm = w & 1, wn = w >> 1;
    const int sr = w * 8 + (lane >> 3);
    const int sp = lane & 7;

    float bvv[4];
    #pragma unroll
    for (int jb = 0; jb < 4; ++jb) bvv[jb] = bias[n0 + wn * 64 + jb * 16 + l16];

    for (int t = 0; t < 2; ++t) {
        const int by = xcd * 8 + byp * 2 + t;
        const int m0 = by * 128;

        f4_t acc[4][4];
        #pragma unroll
        for (int i = 0; i < 4; ++i)
            #pragma unroll
            for (int jb = 0; jb < 4; ++jb) acc[i][jb] = (f4_t){0.f, 0.f, 0.f, 0.f};

        for (int k0 = 0; k0 < DD; k0 += 64) {
            __syncthreads();
            #pragma unroll
            for (int ra = 0; ra < 4; ++ra) {
                const int r = sr + ra * 32;
                const int c = sp ^ (r & 7);
                const int ldso = ra * 2048 + w * 512 + lane * 8;
                gld16(A  + (size_t)(m0 + r) * DD + k0 + c * 8, As + ldso);
                gld16(Wt + (size_t)(n0 + r) * DD + k0 + c * 8, Bs + ldso);
            }
            __syncthreads();
            #pragma unroll
            for (int s = 0; s < 2; ++s) {
                bf8_t a[4], b[4];
                #pragma unroll
                for (int i = 0; i < 4; ++i) {
                    const int rA = wm * 64 + i * 16 + l16;
                    const int pA = (s * 4 + quad) ^ (rA & 7);
                    a[i] = *(const bf8_t*)(As + rA * 64 + pA * 8);
                    const int rB = wn * 64 + i * 16 + l16;
                    const int pB = (s * 4 + quad) ^ (rB & 7);
                    b[i] = *(const bf8_t*)(Bs + rB * 64 + pB * 8);
                }
                #pragma unroll
                for (int i = 0; i < 4; ++i)
                    #pragma unroll
                    for (int jb = 0; jb < 4; ++jb)
                        acc[i][jb] = __builtin_amdgcn_mfma_f32_16x16x32_bf16(a[i], b[jb], acc[i][jb], 0, 0, 0);
            }
        }

        #pragma unroll
        for (int i = 0; i < 4; ++i) {
            #pragma unroll
            for (int jb = 0; jb < 4; ++jb) {
                const int n = n0 + wn * 64 + jb * 16 + l16;
                #pragma unroll
                for (int r = 0; r < 4; ++r) {
                    const int m = m0 + wm * 64 + i * 16 + quad * 4 + r;
                    const float val = acc[i][jb][r] + bvv[jb];
                    const int b_ = m >> 9, l = m & 511;
                    const int h = n >> 6, d = n & 63;
                    if (seg < 2)
                        out[(((size_t)(b_ * HH + h)) * LL + l) * DHH + d] = f2bf(val);
                    else
                        out[(((size_t)(b_ * HH + h)) * DHH + d) * LL + l] = f2bf(val);
                }
            }
        }
    }
}

// ---------------- flash-style MFMA attention --------------------------------
// grid (192, 8): x = h + 12*b, y = qt (qt slowest -> same-(b,h) on one XCD).
// LDS = 24.5 KB (P aliased into the la buffer, see below) -> 6 blocks/CU, and
// 1536 = 256 CU x 6 -> ALL blocks resident in one round, 24 waves/CU (the
// r5-r7 version was 33 KB -> 4/CU, 1.5 rounds, 36% occupancy, latency-bound).
//
// P-alias correctness: the la tile bs16 is used per-wave in 16-row stripes
// (staging: wave w writes rows 16w..16w+15; softmax: wave w reads only
// lrel = 16w+quad*4+r). After softmax the stripe's la values are dead, and
// P (1024 shorts < 1088-short stripe) is written/read by the SAME wave only
// (PV ap-reads). Same-array LDS ops from one wave are compiler-ordered via
// lgkmcnt, and cross-wave sharing never occurs -> no extra barrier needed.
// p = la * exp(s/8 - m): softmax(log la + s/8) without the log.
__global__ __launch_bounds__(256) void attn_mfma(
    const short* __restrict__ Q, const short* __restrict__ K,
    const short* __restrict__ Vt, const short* __restrict__ LA,
    short* __restrict__ out)
{
    __shared__ short Ks[64 * 64];
    __shared__ short Vs[64 * 64];
    __shared__ short bs16[64 * 68];   // la tile; per-wave stripe doubles as P

    const int h = blockIdx.x % 12, b = blockIdx.x / 12;
    const int qt = blockIdx.y;
    const int tid = threadIdx.x;
    const int w = tid >> 6, lane = tid & 63;
    const int quad = lane >> 4, l16 = lane & 15;
    const int q0 = qt * 64;
    const size_t bh = (size_t)b * HH + h;

    const int qr = q0 + w * 16 + l16;
    const bf8_t aq0 = *(const bf8_t*)(Q + (bh * LL + qr) * DHH + quad * 8);
    const bf8_t aq1 = *(const bf8_t*)(Q + (bh * LL + qr) * DHH + quad * 8 + 32);

    f4_t o[4];
    #pragma unroll
    for (int dj = 0; dj < 4; ++dj) o[dj] = (f4_t){0.f, 0.f, 0.f, 0.f};
    float m_row[4], l_row[4];
    #pragma unroll
    for (int r = 0; r < 4; ++r) { m_row[r] = -1e30f; l_row[r] = 0.f; }

    const short* Kg = K  + bh * LL * DHH;
    const short* Vg = Vt + bh * DHH * LL;
    const short* Bg = LA + (bh * LL + q0) * LL;

    const int srow = tid >> 2;
    const int cb   = (tid & 3) * 2;
    const int sw   = srow & 7;
    short* Pw = bs16 + w * (16 * 68);   // own 1088-short stripe; P uses 1024

    for (int t0 = 0; t0 < LL; t0 += 64) {
        __syncthreads();
        {
            const short* src = Kg + (size_t)(t0 + srow) * DHH + cb * 8;
            *(bf8_t*)(Ks + srow * 64 + ((cb ^ sw) * 8))       = *(const bf8_t*)(src);
            *(bf8_t*)(Ks + srow * 64 + (((cb + 1) ^ sw) * 8)) = *(const bf8_t*)(src + 8);
        }
        {
            const short* src = Vg + (size_t)srow * LL + t0 + cb * 8;
            *(bf8_t*)(Vs + srow * 64 + ((cb ^ sw) * 8))       = *(const bf8_t*)(src);
            *(bf8_t*)(Vs + srow * 64 + (((cb + 1) ^ sw) * 8)) = *(const bf8_t*)(src + 8);
        }
        {
            const int l = tid >> 2, ts = (tid & 3) * 16;   // wave w -> rows 16w..16w+15
            const short* src = Bg + (size_t)l * LL + t0 + ts;
            #pragma unroll
            for (int i = 0; i < 4; ++i)
                *(short4*)(bs16 + l * 68 + ts + i * 4) = *(const short4*)(src + i * 4);
        }
        __syncthreads();

        // ---- S = Q K^T ----
        f4_t sv[4];
        #pragma unroll
        for (int j = 0; j < 4; ++j) {
            const int rB = j * 16 + l16;
            const int x = rB & 7;
            const bf8_t b0 = *(const bf8_t*)(Ks + rB * 64 + ((quad ^ x) * 8));
            const bf8_t b1 = *(const bf8_t*)(Ks + rB * 64 + (((quad + 4) ^ x) * 8));
            f4_t c = (f4_t){0.f, 0.f, 0.f, 0.f};
            c = __builtin_amdgcn_mfma_f32_16x16x32_bf16(aq0, b0, c, 0, 0, 0);
            c = __builtin_amdgcn_mfma_f32_16x16x32_bf16(aq1, b1, c, 0, 0, 0);
            sv[j] = c;
        }

        // ---- online softmax: p = la * exp(s/8 - m) ----
        #pragma unroll
        for (int r = 0; r < 4; ++r) {
            const int lrel = w * 16 + quad * 4 + r;
            float mx = fmaxf(fmaxf(sv[0][r], sv[1][r]), fmaxf(sv[2][r], sv[3][r]));
            mx = fmaxf(mx, __shfl_xor(mx, 1, 16));
            mx = fmaxf(mx, __shfl_xor(mx, 2, 16));
            mx = fmaxf(mx, __shfl_xor(mx, 4, 16));
            mx = fmaxf(mx, __shfl_xor(mx, 8, 16));
            const float mn = fmaxf(m_row[r], mx * 0.125f);
            const float al = __expf(m_row[r] - mn);
            m_row[r] = mn;
            float rs = 0.f;
            #pragma unroll
            for (int j = 0; j < 4; ++j) {
                const float lav = bf2f(bs16[lrel * 68 + j * 16 + l16]);
                const float p = lav * __expf(__builtin_fmaf(sv[j][r], 0.125f, -mn));
                sv[j][r] = p;
                rs += p;
            }
            rs += __shfl_xor(rs, 1, 16);
            rs += __shfl_xor(rs, 2, 16);
            rs += __shfl_xor(rs, 4, 16);
            rs += __shfl_xor(rs, 8, 16);
            l_row[r] = l_row[r] * al + rs;
            #pragma unroll
            for (int dj = 0; dj < 4; ++dj) o[dj][r] *= al;
        }
        // ---- P: C-layout -> swizzled LDS (la stripe, now dead) -> A-layout -
        #pragma unroll
        for (int r = 0; r < 4; ++r) {
            const int rp = quad * 4 + r, rp7 = rp & 7;
            #pragma unroll
            for (int j = 0; j < 4; ++j) {
                const int t = j * 16 + l16;
                Pw[rp * 64 + (((t >> 3) ^ rp7) * 8) + (t & 7)] = f2bf(sv[j][r]);
            }
        }
        const int m7 = l16 & 7;
        const bf8_t ap0 = *(const bf8_t*)(Pw + l16 * 64 + ((quad ^ m7) * 8));
        const bf8_t ap1 = *(const bf8_t*)(Pw + l16 * 64 + (((quad + 4) ^ m7) * 8));
        #pragma unroll
        for (int dj = 0; dj < 4; ++dj) {
            const int rB = dj * 16 + l16;
            const int x = rB & 7;
            const bf8_t b0 = *(const bf8_t*)(Vs + rB * 64 + ((quad ^ x) * 8));
            const bf8_t b1 = *(const bf8_t*)(Vs + rB * 64 + (((quad + 4) ^ x) * 8));
            o[dj] = __builtin_amdgcn_mfma_f32_16x16x32_bf16(ap0, b0, o[dj], 0, 0, 0);
            o[dj] = __builtin_amdgcn_mfma_f32_16x16x32_bf16(ap1, b1, o[dj], 0, 0, 0);
        }
    }

    #pragma unroll
    for (int r = 0; r < 4; ++r) {
        const int l = q0 + w * 16 + quad * 4 + r;
        const float inv = 1.f / l_row[r];
        short* op = out + ((size_t)b * LL + l) * DD + h * DHH;
        #pragma unroll
        for (int dj = 0; dj < 4; ++dj)
            op[dj * 16 + l16] = f2bf(o[dj][r] * inv);
    }
}

// ---------------- O-projection GEMM (XCD-swizzled, fp32 out) ----------------
__global__ __launch_bounds__(256) void gemm_o(
    const short* __restrict__ A, const short* __restrict__ Wt,
    const float* __restrict__ bias, float* __restrict__ out)
{
    __shared__ short As[128 * 64];
    __shared__ short Bs[128 * 64];
    const int id = blockIdx.y * 6 + blockIdx.x;
    const int xcd = id & 7, j = id >> 3;          // j: 0..47
    const int by = xcd * 8 + j / 6;
    const int bx = j % 6;
    const int n0 = bx * 128, m0 = by * 128;
    const int tid = threadIdx.x;
    const int w = tid >> 6, lane = tid & 63;
    const int quad = lane >> 4, l16 = lane & 15;
    const int wm = w & 1, wn = w >> 1;
    const int sr = w * 8 + (lane >> 3);
    const int sp = lane & 7;

    f4_t acc[4][4];
    #pragma unroll
    for (int i = 0; i < 4; ++i)
        #pragma unroll
        for (int jj = 0; jj < 4; ++jj) acc[i][jj] = (f4_t){0.f, 0.f, 0.f, 0.f};

    for (int k0 = 0; k0 < DD; k0 += 64) {
        __syncthreads();
        #pragma unroll
        for (int ra = 0; ra < 4; ++ra) {
            const int r = sr + ra * 32;
            const int c = sp ^ (r & 7);
            const int ldso = ra * 2048 + w * 512 + lane * 8;
            gld16(A  + (size_t)(m0 + r) * DD + k0 + c * 8, As + ldso);
            gld16(Wt + (size_t)(n0 + r) * DD + k0 + c * 8, Bs + ldso);
        }
        __syncthreads();
        #pragma unroll
        for (int s = 0; s < 2; ++s) {
            bf8_t a[4], b[4];
            #pragma unroll
            for (int i = 0; i < 4; ++i) {
                const int rA = wm * 64 + i * 16 + l16;
                const int pA = (s * 4 + quad) ^ (rA & 7);
                a[i] = *(const bf8_t*)(As + rA * 64 + pA * 8);
                const int rB = wn * 64 + i * 16 + l16;
                const int pB = (s * 4 + quad) ^ (rB & 7);
                b[i] = *(const bf8_t*)(Bs + rB * 64 + pB * 8);
            }
            #pragma unroll
            for (int i = 0; i < 4; ++i)
                #pragma unroll
                for (int jj = 0; jj < 4; ++jj)
                    acc[i][jj] = __builtin_amdgcn_mfma_f32_16x16x32_bf16(a[i], b[jj], acc[i][jj], 0, 0, 0);
        }
    }

    float bvv[4];
    #pragma unroll
    for (int jj = 0; jj < 4; ++jj) bvv[jj] = bias[n0 + wn * 64 + jj * 16 + l16];
    #pragma unroll
    for (int i = 0; i < 4; ++i)
        #pragma unroll
        for (int jj = 0; jj < 4; ++jj) {
            const int n = n0 + wn * 64 + jj * 16 + l16;
            #pragma unroll
            for (int r = 0; r < 4; ++r) {
                const int m = m0 + wm * 64 + i * 16 + quad * 4 + r;
                out[(size_t)m * DD + n] = acc[i][jj][r] + bvv[jj];
            }
        }
}

// ---------------- residual + LayerNorm --------------------------------------
__global__ __launch_bounds__(256) void ln_kernel(
    const float* __restrict__ x, const float* __restrict__ tgt,
    const float* __restrict__ g, const float* __restrict__ bta,
    float* __restrict__ out)
{
    const int row = blockIdx.x;
    const int tid = threadIdx.x;
    __shared__ float red[4];

    const float* xp = x + (size_t)row * DD;
    const float* tp = tgt + (size_t)row * DD;

    float vals[3];
    float s = 0.f;
    #pragma unroll
    for (int i = 0; i < 3; ++i) {
        const float v = xp[tid + i * 256] + tp[tid + i * 256];
        vals[i] = v;
        s += v;
    }
    s = block_sum(s, red, tid);
    const float mu = s * (1.f / 768.f);

    float vs = 0.f;
    #pragma unroll
    for (int i = 0; i < 3; ++i) {
        const float dv = vals[i] - mu;
        vs += dv * dv;
    }
    vs = block_sum(vs, red, tid);
    const float rstd = rsqrtf(vs * (1.f / 768.f) + LN_EPS);

    #pragma unroll
    for (int i = 0; i < 3; ++i) {
        const int cidx = tid + i * 256;
        out[(size_t)row * DD + cidx] = g[cidx] * (vals[i] - mu) * rstd + bta[cidx];
    }
}

// ---------------- launch -----------------------------------------------------
extern "C" void kernel_launch(void* const* d_in, const int* in_sizes, int n_in,
                              void* d_out, int out_size, void* d_ws, size_t ws_size,
                              hipStream_t stream) {
    const float* tgt   = (const float*)d_in[0];
    const float* qpos  = (const float*)d_in[1];
    const float* ploc  = (const float*)d_in[2];
    const float* Wq    = (const float*)d_in[3];
    const float* bq    = (const float*)d_in[4];
    const float* Wk    = (const float*)d_in[5];
    const float* bk    = (const float*)d_in[6];
    const float* Wv    = (const float*)d_in[7];
    const float* bv    = (const float*)d_in[8];
    const float* Wo    = (const float*)d_in[9];
    const float* bo    = (const float*)d_in[10];
    const float* Wloc  = (const float*)d_in[11];
    const float* bloc  = (const float*)d_in[12];
    const float* ln_g  = (const float*)d_in[13];
    const float* ln_b  = (const float*)d_in[14];

    const size_t NQ = (size_t)MM * DD;           // 6291456
    const size_t NW = (size_t)DD * DD;           // 589824

    short* qb   = (short*)d_ws;
    short* kb   = qb  + NQ;
    short* vtb  = kb  + NQ;
    short* aob  = vtb + NQ;
    short* aqk  = aob + NQ;
    short* av   = aqk + NQ;
    float* pbuf = (float*)aqk;                   // alias (aqk,av dead by then)
    short* wqt  = av + NQ;
    short* wkt  = wqt + NW;
    short* wvt  = wkt + NW;
    short* wot  = wvt + NW;
    short* lab  = wot + NW;

    prep_kernel<<<3648, 256, 0, stream>>>(tgt, qpos, Wq, Wk, Wv, Wo,
                                          aqk, av, wqt, wkt, wvt, wot);

    qkv_la<<<2624, 256, 0, stream>>>(aqk, av, wqt, bq, qb,
                                     wkt, bk, kb, wvt, bv, vtb,
                                     ploc, Wloc, bloc, lab);

    attn_mfma<<<dim3(192, 8), 256, 0, stream>>>(qb, kb, vtb, lab, aob);

    gemm_o<<<dim3(6, 64), 256, 0, stream>>>(aob, wot, bo, pbuf);

    ln_kernel<<<MM, 256, 0, stream>>>(pbuf, tgt, ln_g, ln_b, (float*)d_out);
}